// Round 1
// baseline (516.839 us; speedup 1.0000x reference)
//
#include <hip/hip_runtime.h>

// SpectralClassifier: the DCT-II -> bandpass(k in [0,15)) -> IDCT -> mean(m)
// chain collapses analytically: sum_m IDCT-basis(m,k) == 0 for all k>=1
// (sum_{m=0}^{N-1} cos((2m+1)pi k/2N) = sin(pi k)/(2 sin(pi k/2N)) = 0), so
// only the k=0 (DC) term survives:
//   v[b,d] = (1/127) * sum_{s=1..127} mask[b,s] * hidden[b,s,d]
// followed by the 768->256->64->2 ReLU MLP.
//
// NOTE on dur_us: harness reset traffic (1.5 GiB 0xAA poison fill ~248 us +
// 402 MB hidden restore ~125 us) dominates the reported duration; the two
// kernels below are a ~45-60 us slice. Optimizations target that slice.
//
// R1 changes vs previous best (512.0 us):
//  - Kernel 2 layer 1 was LDS-issue-bound: 3072 broadcast ds_read_b128/CU
//    x ~12 cyc = 36.9K cyc (~15 us) vs 6.1K cyc of FMA. The x operands are
//    wave-uniform, so they now come from global v with a block-uniform
//    address (compiler emits s_load; v_fma takes one SGPR operand). Layer-1
//    LDS traffic -> 0; kernel 2 becomes W1-L2-stream-bound (~6-8 us).
//  - Kernel 1 compaction: __ballot/popcount ranking replaces ~127 serialized
//    LDS atomicAdds per block.

#define BB   1024
#define SS   128
#define DD   768
#define VEC4 (DD / 4)   // 192 float4 per row

// native clang vector type: required by __builtin_nontemporal_load
// (HIP's float4 is a struct and is rejected by the builtin)
typedef float floatx4 __attribute__((ext_vector_type(4)));

// ---------------- Kernel 1: masked row-sum over seq (HBM-bound) ------------
// One block per batch, 192 threads = one float4 column each. Active seq
// positions are compacted (as precomputed float4 offsets) into LDS so the
// inner loop is branch-free and masked-out rows are never fetched
// (~201 MB instead of 402 MB for the ~50%-dense mask).
//
// Mask dtype: bool is marshaled as int32 by the harness; a cheap PARALLEL
// probe (128 threads, one putative int32 element each) keeps us robust to
// uint8 marshaling without serial-loop latency.
__global__ __launch_bounds__(192) void spectral_reduce_kernel(
    const float* __restrict__ hidden,        // [B,S,D]
    const unsigned char* __restrict__ mask8, // [B,S] bool: int32 or uint8
    float* __restrict__ v)                   // [B,D]
{
    const int b = blockIdx.x;
    const int t = threadIdx.x;  // 0..191

    __shared__ int slist[SS];
    __shared__ int wcnt[2];
    __shared__ int not_i32;
    if (t == 0) not_i32 = 0;
    __syncthreads();

    if (t < 128) {
        // bytes 1..3 of putative int32 element t: nonzero => not int32 {0,1}
        const unsigned char* p = mask8 + 4 * t;
        if (p[1] | p[2] | p[3]) not_i32 = 1;   // benign race, same value
    }
    __syncthreads();

    const int as_i32 = !not_i32;

    // ballot-based compaction of active positions 1..127 (CLS at s=0 dropped).
    // Waves 0 and 1 cover s=0..127; wave 2 (t>=128) contributes mv=0.
    const int lane = t & 63;
    const int w    = t >> 6;
    int mv = 0;
    if (t >= 1 && t < 128) {
        size_t idx = (size_t)b * SS + t;
        mv = as_i32 ? (((const int*)mask8)[idx] != 0) : (mask8[idx] != 0);
    }
    unsigned long long bm = __ballot(mv);
    if (lane == 0 && w < 2) wcnt[w] = (int)__popcll(bm);
    const int rank = (int)__popcll(bm & ((1ull << lane) - 1ull));
    __syncthreads();

    if (mv) slist[(w ? wcnt[0] : 0) + rank] = t * VEC4;  // float4 offset
    const int n = wcnt[0] + wcnt[1];
    __syncthreads();

    const floatx4* hp = (const floatx4*)(hidden + (size_t)b * SS * DD);

    // hidden is streamed exactly once -> nontemporal, keep L2/L3 for weights
    floatx4 a0 = (floatx4)0.f;
    floatx4 a1 = (floatx4)0.f;
    int i = 0;
    for (; i + 7 < n; i += 8) {                // 8 loads in flight per lane
        floatx4 x0 = __builtin_nontemporal_load(&hp[slist[i + 0] + t]);
        floatx4 x1 = __builtin_nontemporal_load(&hp[slist[i + 1] + t]);
        floatx4 x2 = __builtin_nontemporal_load(&hp[slist[i + 2] + t]);
        floatx4 x3 = __builtin_nontemporal_load(&hp[slist[i + 3] + t]);
        floatx4 x4 = __builtin_nontemporal_load(&hp[slist[i + 4] + t]);
        floatx4 x5 = __builtin_nontemporal_load(&hp[slist[i + 5] + t]);
        floatx4 x6 = __builtin_nontemporal_load(&hp[slist[i + 6] + t]);
        floatx4 x7 = __builtin_nontemporal_load(&hp[slist[i + 7] + t]);
        a0 += x0; a1 += x1; a0 += x2; a1 += x3;
        a0 += x4; a1 += x5; a0 += x6; a1 += x7;
    }
    for (; i < n; ++i) {
        a0 += __builtin_nontemporal_load(&hp[slist[i] + t]);
    }
    a0 += a1;

    const float sc = 1.0f / 127.0f;
    floatx4 r = a0 * sc;
    ((floatx4*)(v + (size_t)b * DD))[t] = r;   // cached: kernel 2 re-reads it
}

// ---------------- Kernel 2: fused 3-layer MLP ------------------------------
// BM=4 batch rows per block, 256 threads, 256 blocks (1/CU). W1 (768 KB)
// is read once per block from L2/L3 (197 MB aggregate @ ~34 TB/s ~ 6 us).
// Layer-1 activations are read with BLOCK-UNIFORM global loads (address is
// blockIdx + loop counter only): the compiler scalarizes them to s_load and
// the FMA takes the SGPR operand directly -> zero LDS traffic in layer 1
// (previously 3072 broadcast ds_read_b128/CU ~ 15 us, the kernel's real
// bottleneck). Layers 2/3 keep small uniform ds_read_b128 broadcasts.
#define BM 4
__global__ __launch_bounds__(256) void spectral_mlp_kernel(
    const float* __restrict__ v,   // [B,D]
    const float* __restrict__ W1, const float* __restrict__ b1,  // [768,256],[256]
    const float* __restrict__ W2, const float* __restrict__ b2,  // [256,64],[64]
    const float* __restrict__ W3, const float* __restrict__ b3,  // [64,2],[2]
    float* __restrict__ out)       // [B,2]
{
    __shared__ float h1[BM][256];     // 4 KB
    __shared__ float h2[BM][64];      // 1 KB

    const int t  = threadIdx.x;
    const int b0 = blockIdx.x * BM;
    const float* __restrict__ vb = v + (size_t)b0 * DD;  // block-uniform base

    // ---- layer 1: thread owns output column j = t for all 4 rows ----
    {
        float a0 = b1[t], a1 = a0, a2 = a0, a3 = a0;
        #pragma unroll 4
        for (int k = 0; k < DD; k += 4) {
            // block-uniform addresses -> scalar loads (s_load_dwordx4)
            floatx4 x0 = *(const floatx4*)(vb + 0 * DD + k);
            floatx4 x1 = *(const floatx4*)(vb + 1 * DD + k);
            floatx4 x2 = *(const floatx4*)(vb + 2 * DD + k);
            floatx4 x3 = *(const floatx4*)(vb + 3 * DD + k);
            float w0 = W1[(k + 0) * 256 + t];  // coalesced 1 KB/step
            float w1 = W1[(k + 1) * 256 + t];
            float w2 = W1[(k + 2) * 256 + t];
            float w3 = W1[(k + 3) * 256 + t];
            a0 = fmaf(x0.x, w0, a0); a0 = fmaf(x0.y, w1, a0);
            a0 = fmaf(x0.z, w2, a0); a0 = fmaf(x0.w, w3, a0);
            a1 = fmaf(x1.x, w0, a1); a1 = fmaf(x1.y, w1, a1);
            a1 = fmaf(x1.z, w2, a1); a1 = fmaf(x1.w, w3, a1);
            a2 = fmaf(x2.x, w0, a2); a2 = fmaf(x2.y, w1, a2);
            a2 = fmaf(x2.z, w2, a2); a2 = fmaf(x2.w, w3, a2);
            a3 = fmaf(x3.x, w0, a3); a3 = fmaf(x3.y, w1, a3);
            a3 = fmaf(x3.z, w2, a3); a3 = fmaf(x3.w, w3, a3);
        }
        h1[0][t] = fmaxf(a0, 0.f);
        h1[1][t] = fmaxf(a1, 0.f);
        h1[2][t] = fmaxf(a2, 0.f);
        h1[3][t] = fmaxf(a3, 0.f);
    }
    __syncthreads();

    // ---- layer 2: 4 rows x 64 cols = 256 outputs, one per thread ----
    {
        const int r = t >> 6;      // wave-uniform (64-lane waves)
        const int j = t & 63;
        float a = b2[j];
        const floatx4* hr = (const floatx4*)h1[r];  // 1 KB-aligned
        #pragma unroll 4
        for (int i4 = 0; i4 < 64; ++i4) {
            floatx4 x = hr[i4];                 // ds_read_b128, broadcast
            a = fmaf(x.x, W2[(4 * i4 + 0) * 64 + j], a);
            a = fmaf(x.y, W2[(4 * i4 + 1) * 64 + j], a);
            a = fmaf(x.z, W2[(4 * i4 + 2) * 64 + j], a);
            a = fmaf(x.w, W2[(4 * i4 + 3) * 64 + j], a);
        }
        h2[r][j] = fmaxf(a, 0.f);
    }
    __syncthreads();

    // ---- layer 3: 4 rows x 2 logits ----
    if (t < BM * 2) {
        const int r = t >> 1;
        const int c = t & 1;
        float a = b3[c];
        const floatx4* hr = (const floatx4*)h2[r];
        #pragma unroll
        for (int i4 = 0; i4 < 16; ++i4) {
            floatx4 x = hr[i4];
            a = fmaf(x.x, W3[(4 * i4 + 0) * 2 + c], a);
            a = fmaf(x.y, W3[(4 * i4 + 1) * 2 + c], a);
            a = fmaf(x.z, W3[(4 * i4 + 2) * 2 + c], a);
            a = fmaf(x.w, W3[(4 * i4 + 3) * 2 + c], a);
        }
        out[(size_t)(b0 + r) * 2 + c] = a;
    }
}

extern "C" void kernel_launch(void* const* d_in, const int* in_sizes, int n_in,
                              void* d_out, int out_size, void* d_ws, size_t ws_size,
                              hipStream_t stream) {
    const float*         hidden = (const float*)d_in[0];
    const unsigned char* mask   = (const unsigned char*)d_in[1];  // dtype probed in-kernel
    const float*         W1     = (const float*)d_in[2];
    const float*         b1     = (const float*)d_in[3];
    const float*         W2     = (const float*)d_in[4];
    const float*         b2     = (const float*)d_in[5];
    const float*         W3     = (const float*)d_in[6];
    const float*         b3     = (const float*)d_in[7];
    float*               out    = (float*)d_out;

    float* v = (float*)d_ws;  // [B, D] = 3 MB scratch

    spectral_reduce_kernel<<<BB, 192, 0, stream>>>(hidden, mask, v);
    spectral_mlp_kernel<<<BB / BM, 256, 0, stream>>>(v, W1, b1, W2, b2, W3, b3, out);
}